// Round 5
// baseline (1519.820 us; speedup 1.0000x reference)
//
#include <hip/hip_runtime.h>
#include <hip/hip_bf16.h>

// MLPSCM round 5: OUTPUT IS FLOAT32 (reference returns fp32; harness header:
// "else float*"). R2-R4's identical full-scale absmax was the harness decoding
// my packed-bf16 buffer as fp32 -> scrambled-but-right-magnitude values.
// Input path unchanged (hardware-verified by R4's clean diagnostics):
//   fp32 inputs, int32 mask/act_id, content-disambiguated W vs mask,
//   thread-per-sample, vals[240] fp32 in LDS, j-chunked by 16.

constexpr int S_LEN    = 131072;
constexpr int N_NODES  = 256;
constexpr int N_CAUSES = 16;
constexpr int N_COMP   = 240;
constexpr int N_FEAT   = 100;
constexpr int TS       = 64;     // block = 1 wave
constexpr float NOISE  = 0.01f;

__device__ float g_Wm[N_NODES * N_NODES];   // masked W, fp32, [p][j]

// ---------- content sniffers (uniform broadcast loads, ~free) ----------
__device__ __forceinline__ bool sniff_binary64(const void* p) {
    const unsigned* u = (const unsigned*)p;
    bool ok = true;
    for (int i = 0; i < 64; ++i) ok = ok && (u[i] <= 1u);
    return ok;   // int32 {0,1} mask passes; N(0,1) float data cannot
}
__device__ __forceinline__ bool sniff_is_bf16(const void* p) {
    const unsigned* u = (const unsigned*)p;
    bool ok = true;
    for (int i = 0; i < 16; ++i) {
        unsigned e = ((u[i] << 16) >> 23) & 0xffu;
        ok = ok && (e >= 100u) && (e <= 132u);
    }
    return ok;
}
__device__ __forceinline__ float bflo(unsigned u) { return __uint_as_float(u << 16); }
__device__ __forceinline__ float bfhi(unsigned u) { return __uint_as_float(u & 0xffff0000u); }

__device__ __forceinline__ void load16(const void* base, long long off, bool isbf, float* o) {
    if (isbf) {
        const uint4* p = (const uint4*)((const unsigned short*)base + off);
        uint4 a = p[0], b = p[1];
        o[0]=bflo(a.x); o[1]=bfhi(a.x); o[2]=bflo(a.y); o[3]=bfhi(a.y);
        o[4]=bflo(a.z); o[5]=bfhi(a.z); o[6]=bflo(a.w); o[7]=bfhi(a.w);
        o[8]=bflo(b.x); o[9]=bfhi(b.x); o[10]=bflo(b.y); o[11]=bfhi(b.y);
        o[12]=bflo(b.z); o[13]=bfhi(b.z); o[14]=bflo(b.w); o[15]=bfhi(b.w);
    } else {
        const float4* p = (const float4*)((const float*)base + off);
        float4 x0=p[0], x1=p[1], x2=p[2], x3=p[3];
        o[0]=x0.x; o[1]=x0.y; o[2]=x0.z; o[3]=x0.w;
        o[4]=x1.x; o[5]=x1.y; o[6]=x1.z; o[7]=x1.w;
        o[8]=x2.x; o[9]=x2.y; o[10]=x2.z; o[11]=x2.w;
        o[12]=x3.x; o[13]=x3.y; o[14]=x3.z; o[15]=x3.w;
    }
}

// ---------- kernels ----------
__global__ void prep_kernel(const void* __restrict__ A, const void* __restrict__ B) {
    __shared__ int s_mA, s_wbf;
    if (threadIdx.x == 0) {
        const int mA = sniff_binary64(A) ? 1 : 0;   // which of {A,B} is the mask
        s_mA  = mA;
        s_wbf = sniff_is_bf16(mA ? B : A) ? 1 : 0;
    }
    __syncthreads();
    const int*  maskp = (const int*)(s_mA ? A : B);
    const void* Wp    = s_mA ? B : A;
    int i = blockIdx.x * blockDim.x + threadIdx.x;
    float w = s_wbf ? __bfloat162float(((const __hip_bfloat16*)Wp)[i])
                    : ((const float*)Wp)[i];
    g_Wm[i] = maskp[i] ? w : 0.0f;
}

#define FMA16(w0, w1, w2, w3, v)                                                      \
    acc[0]  += (w0).x * (v); acc[1]  += (w0).y * (v);                                 \
    acc[2]  += (w0).z * (v); acc[3]  += (w0).w * (v);                                 \
    acc[4]  += (w1).x * (v); acc[5]  += (w1).y * (v);                                 \
    acc[6]  += (w1).z * (v); acc[7]  += (w1).w * (v);                                 \
    acc[8]  += (w2).x * (v); acc[9]  += (w2).y * (v);                                 \
    acc[10] += (w2).z * (v); acc[11] += (w2).w * (v);                                 \
    acc[12] += (w3).x * (v); acc[13] += (w3).y * (v);                                 \
    acc[14] += (w3).z * (v); acc[15] += (w3).w * (v);

__global__ __launch_bounds__(TS)
void scm_kernel(const void* __restrict__ causes,
                const void* __restrict__ eps,
                const int* __restrict__ act_id,
                const void* __restrict__ xidx_raw,
                const int* __restrict__ yidx_raw,
                float* __restrict__ out,
                long long ybase) {
    __shared__ float vals[N_COMP][TS];   // 61440 B
    __shared__ int   ixs[N_FEAT];

    const int tid = threadIdx.x;
    const long long s = (long long)blockIdx.x * TS + tid;

    const bool cbf = sniff_is_bf16(causes);
    const bool ebf = sniff_is_bf16(eps);

    const long long* xi64 = (const long long*)xidx_raw;
    const int*       xi32 = (const int*)xidx_raw;
    const bool is64 = ((((const unsigned long long*)xidx_raw)[0] >> 32) == 0ull);
    for (int f = tid; f < N_FEAT; f += TS)
        ixs[f] = (is64 ? (int)xi64[f] : xi32[f]) - N_CAUSES;

    float cv[N_CAUSES];
    load16(causes, s * N_CAUSES, cbf, cv);

    for (int k = 1; k < 16; ++k) {
        const int j0 = 16 * k;
        float acc[16];
        #pragma unroll
        for (int i = 0; i < 16; ++i) acc[i] = 0.0f;

        // parents among causes (registers)
        #pragma unroll
        for (int p = 0; p < N_CAUSES; ++p) {
            const float4* wr = (const float4*)(g_Wm + p * N_NODES + j0);
            float4 w0 = wr[0], w1 = wr[1], w2 = wr[2], w3 = wr[3];
            const float v = cv[p];
            FMA16(w0, w1, w2, w3, v)
        }
        // parents among previously computed nodes (LDS)
        #pragma unroll 4
        for (int p = N_CAUSES; p < j0; ++p) {
            const float4* wr = (const float4*)(g_Wm + p * N_NODES + j0);
            float4 w0 = wr[0], w1 = wr[1], w2 = wr[2], w3 = wr[3];
            const float v = vals[p - N_CAUSES][tid];
            FMA16(w0, w1, w2, w3, v)
        }

        float ev[16];
        load16(eps, s * (long long)N_COMP + (j0 - N_CAUSES), ebf, ev);

        // sequential intra-chunk part
        float vnew[16];
        #pragma unroll
        for (int i = 0; i < 16; ++i) {
            float z = acc[i];
            #pragma unroll
            for (int l = 0; l < i; ++l)
                z += g_Wm[(j0 + l) * N_NODES + (j0 + i)] * vnew[l];
            z += NOISE * ev[i];
            const int a = act_id[j0 - N_CAUSES + i];   // wave-uniform
            if (a == 1)      z = tanhf(z);
            else if (a == 2) z = fmaxf(z, 0.0f);
            else if (a == 3) z = 1.0f / (1.0f + expf(-z));
            vnew[i] = z;
            vals[j0 - N_CAUSES + i][tid] = z;
        }
    }

    __syncthreads();

    // ---- X output: fp32, per-thread row-contiguous float4 stores ----
    const long long xrow = s * (long long)N_FEAT;   // 400 B/row, 16B-aligned
    #pragma unroll
    for (int f0 = 0; f0 < N_FEAT; f0 += 4) {
        float4 pk;
        pk.x = vals[ixs[f0 + 0]][tid];
        pk.y = vals[ixs[f0 + 1]][tid];
        pk.z = vals[ixs[f0 + 2]][tid];
        pk.w = vals[ixs[f0 + 3]][tid];
        *(float4*)(out + xrow + f0) = pk;
    }

    // ---- y output: fp32 ----
    const int yi = yidx_raw[0];   // low word valid for int32 or int64 storage
    out[ybase + s] = vals[yi - N_CAUSES][tid];
}

extern "C" void kernel_launch(void* const* d_in, const int* in_sizes, int n_in,
                              void* d_out, int out_size, void* d_ws, size_t ws_size,
                              hipStream_t stream) {
    // resolve inputs by element count (permutation-proof); fall back to dict order
    int ic = 0, iw = 1, ie = 2, im = 3, ia = 4, ix = 5, iy = 6;
    int c = -1, e = -1, a = -1, x = -1, y = -1, m1 = -1, m2 = -1;
    for (int i = 0; i < n_in; ++i) {
        switch (in_sizes[i]) {
            case S_LEN * N_CAUSES:   c = i; break;
            case S_LEN * N_COMP:     e = i; break;
            case N_COMP:             a = i; break;
            case N_FEAT:             x = i; break;
            case 1:                  y = i; break;
            case N_NODES * N_NODES:  (m1 < 0 ? m1 : m2) = i; break;
        }
    }
    if (c >= 0 && e >= 0 && a >= 0 && x >= 0 && y >= 0 && m1 >= 0 && m2 >= 0) {
        ic = c; ie = e; ia = a; ix = x; iy = y; iw = m1; im = m2;
    }

    const void* causes = d_in[ic];
    const void* TA     = d_in[iw];   // one of {W, mask} — device disambiguates
    const void* TB     = d_in[im];
    const void* eps    = d_in[ie];
    const int*  act_id = (const int*)d_in[ia];
    const void* xidx   = d_in[ix];
    const int*  yidx   = (const int*)d_in[iy];
    float*      out    = (float*)d_out;
    const long long ybase = (long long)out_size - S_LEN;   // = S*100

    prep_kernel<<<(N_NODES * N_NODES) / 256, 256, 0, stream>>>(TA, TB);
    scm_kernel<<<S_LEN / TS, TS, 0, stream>>>(causes, eps, act_id, xidx, yidx, out, ybase);
}

// Round 8
// 556.375 us; speedup vs baseline: 2.7316x; 2.7316x over previous
//
#include <hip/hip_runtime.h>
#include <hip/hip_bf16.h>
#include <hip/hip_fp16.h>

// MLPSCM round 8: R7 design, vals stored as SCALED FP16 (v/16) instead of bf16.
// R7 failed by 1.4% (absmax 2128 vs 2099): bf16's 7 mantissa bits amplify
// through the DAG's multiplicative gain chains. fp16 = 8x finer; /16 scaling
// gives 1.05e6 range (10x margin over observed 1.05e5 max).
//  - vals fp16/16 (fp32 compute), 128 samples/block -> 4 waves/CU
//  - block = 2 waves; waves split parent range, LDS reduction, wave0 tail
//  - W premasked+packed per-chunk tiles, staged to LDS once per chunk
//  - 2 samples per lane; X/y written fp32 straight from tail registers

constexpr int S_LEN    = 131072;
constexpr int N_NODES  = 256;
constexpr int N_CAUSES = 16;
constexpr int N_COMP   = 240;
constexpr int N_FEAT   = 100;
constexpr int TSB      = 128;    // samples per block
constexpr int NTHREADS = 128;    // 2 waves
constexpr float NOISE  = 0.01f;
constexpr float VSC    = 0.0625f;   // store scale (1/16)
constexpr float VSCI   = 16.0f;     // load unscale
constexpr int WPACK_LEN = 34560; // sum over k of (16k+16)*16

__device__ __align__(16) float g_Wpack[WPACK_LEN];

__device__ __forceinline__ int wpack_off(int k) { return 128 * (k - 1) * (k + 2); }

// ---------- content sniffers ----------
__device__ __forceinline__ bool sniff_binary64(const void* p) {
    const unsigned* u = (const unsigned*)p;
    bool ok = true;
    for (int i = 0; i < 64; ++i) ok = ok && (u[i] <= 1u);
    return ok;
}
__device__ __forceinline__ bool sniff_is_bf16(const void* p) {
    const unsigned* u = (const unsigned*)p;
    bool ok = true;
    for (int i = 0; i < 16; ++i) {
        unsigned e = ((u[i] << 16) >> 23) & 0xffu;
        ok = ok && (e >= 100u) && (e <= 132u);
    }
    return ok;
}
__device__ __forceinline__ float bflo(unsigned u) { return __uint_as_float(u << 16); }
__device__ __forceinline__ float bfhi(unsigned u) { return __uint_as_float(u & 0xffff0000u); }

__device__ __forceinline__ void load16(const void* base, long long off, bool isbf, float* o) {
    if (isbf) {
        const uint4* p = (const uint4*)((const unsigned short*)base + off);
        uint4 a = p[0], b = p[1];
        o[0]=bflo(a.x); o[1]=bfhi(a.x); o[2]=bflo(a.y); o[3]=bfhi(a.y);
        o[4]=bflo(a.z); o[5]=bfhi(a.z); o[6]=bflo(a.w); o[7]=bfhi(a.w);
        o[8]=bflo(b.x); o[9]=bfhi(b.x); o[10]=bflo(b.y); o[11]=bfhi(b.y);
        o[12]=bflo(b.z); o[13]=bfhi(b.z); o[14]=bflo(b.w); o[15]=bfhi(b.w);
    } else {
        const float4* p = (const float4*)((const float*)base + off);
        float4 x0=p[0], x1=p[1], x2=p[2], x3=p[3];
        o[0]=x0.x; o[1]=x0.y; o[2]=x0.z; o[3]=x0.w;
        o[4]=x1.x; o[5]=x1.y; o[6]=x1.z; o[7]=x1.w;
        o[8]=x2.x; o[9]=x2.y; o[10]=x2.z; o[11]=x2.w;
        o[12]=x3.x; o[13]=x3.y; o[14]=x3.z; o[15]=x3.w;
    }
}

// pack two fp32 as scaled fp16 pair
__device__ __forceinline__ unsigned pack_h2(float a, float b) {
    union { __half2 h2; unsigned u; } c;
    c.h2 = __floats2half2_rn(a * VSC, b * VSC);
    return c.u;
}
__device__ __forceinline__ float2 unpack_h2(unsigned v) {
    union { unsigned u; __half2 h2; } c; c.u = v;
    float2 f = __half22float2(c.h2);
    f.x *= VSCI; f.y *= VSCI;
    return f;
}

// ---------- prep: masked W packed as per-chunk tiles [rows 0..j0+15][16 cols] ----------
__global__ void prep_kernel(const void* __restrict__ A, const void* __restrict__ B) {
    __shared__ int s_mA, s_wbf;
    if (threadIdx.x == 0) {
        const int mA = sniff_binary64(A) ? 1 : 0;
        s_mA  = mA;
        s_wbf = sniff_is_bf16(mA ? B : A) ? 1 : 0;
    }
    __syncthreads();
    const int*  maskp = (const int*)(s_mA ? A : B);
    const void* Wp    = s_mA ? B : A;
    const int k  = blockIdx.y + 1;
    const int j0 = 16 * k;
    const int L  = (j0 + 16) * 16;
    const int idx = blockIdx.x * 256 + threadIdx.x;
    if (idx < L) {
        const int p = idx >> 4, j = j0 + (idx & 15);
        const int gi = p * N_NODES + j;
        const float w = s_wbf ? __bfloat162float(((const __hip_bfloat16*)Wp)[gi])
                              : ((const float*)Wp)[gi];
        g_Wpack[wpack_off(k) + idx] = maskp[gi] ? w : 0.0f;
    }
}

#define FMA16P(w0, w1, w2, w3, vA, vB)                                                \
    acc0[0]  += (w0).x*(vA); acc1[0]  += (w0).x*(vB);                                 \
    acc0[1]  += (w0).y*(vA); acc1[1]  += (w0).y*(vB);                                 \
    acc0[2]  += (w0).z*(vA); acc1[2]  += (w0).z*(vB);                                 \
    acc0[3]  += (w0).w*(vA); acc1[3]  += (w0).w*(vB);                                 \
    acc0[4]  += (w1).x*(vA); acc1[4]  += (w1).x*(vB);                                 \
    acc0[5]  += (w1).y*(vA); acc1[5]  += (w1).y*(vB);                                 \
    acc0[6]  += (w1).z*(vA); acc1[6]  += (w1).z*(vB);                                 \
    acc0[7]  += (w1).w*(vA); acc1[7]  += (w1).w*(vB);                                 \
    acc0[8]  += (w2).x*(vA); acc1[8]  += (w2).x*(vB);                                 \
    acc0[9]  += (w2).y*(vA); acc1[9]  += (w2).y*(vB);                                 \
    acc0[10] += (w2).z*(vA); acc1[10] += (w2).z*(vB);                                 \
    acc0[11] += (w2).w*(vA); acc1[11] += (w2).w*(vB);                                 \
    acc0[12] += (w3).x*(vA); acc1[12] += (w3).x*(vB);                                 \
    acc0[13] += (w3).y*(vA); acc1[13] += (w3).y*(vB);                                 \
    acc0[14] += (w3).z*(vA); acc1[14] += (w3).z*(vB);                                 \
    acc0[15] += (w3).w*(vA); acc1[15] += (w3).w*(vB);

__global__ __launch_bounds__(NTHREADS, 1)
void scm_kernel(const void* __restrict__ causes,
                const void* __restrict__ eps,
                const int* __restrict__ act_id,
                const void* __restrict__ xidx_raw,
                const int* __restrict__ yidx_raw,
                float* __restrict__ out,
                long long ybase) {
    __shared__ unsigned short vals[N_COMP * TSB];   // 61440 B  (fp16/16, [node-16][sample])
    __shared__ float Wt[4096];                      // 16384 B  (chunk tile; red aliases)
    __shared__ short xpos[N_COMP];                  // 480 B
    __shared__ int   acts[N_COMP];                  // 960 B

    const int tid  = threadIdx.x;
    const int wave = tid >> 6;
    const int lane = tid & 63;
    const long long sA = (long long)blockIdx.x * TSB + 2 * lane;
    const long long sB = sA + 1;

    // --- init tables (strided: 128 threads cover 240 entries) ---
    for (int t = tid; t < N_COMP; t += NTHREADS) { xpos[t] = -1; acts[t] = act_id[t]; }
    const unsigned long long* x64 = (const unsigned long long*)xidx_raw;
    const int*                x32 = (const int*)xidx_raw;
    const bool is64 = ((x64[0] >> 32) == 0ull);
    __syncthreads();
    if (tid < N_FEAT) {
        const int ix = is64 ? (int)x64[tid] : x32[tid];
        xpos[ix - N_CAUSES] = (short)tid;
    }
    const int yi = yidx_raw[0];

    const bool cbf = sniff_is_bf16(causes);
    const bool ebf = sniff_is_bf16(eps);

    // --- causes in registers (wave0 only uses them) ---
    float cv0[N_CAUSES], cv1[N_CAUSES];
    if (wave == 0) {
        load16(causes, sA * N_CAUSES, cbf, cv0);
        load16(causes, sB * N_CAUSES, cbf, cv1);
    }

    // --- stage tile k=1 ---
    {
        const int L = 32 * 16, off = wpack_off(1);
        for (int i = tid * 4; i < L; i += NTHREADS * 4)
            *(float4*)&Wt[i] = *(const float4*)&g_Wpack[off + i];
    }
    __syncthreads();

    for (int k = 1; k < 16; ++k) {
        const int j0 = 16 * k;

        // prefetch eps for the tail (wave0 only) — latency hidden under GEMM
        float evA[16], evB[16];
        if (wave == 0) {
            load16(eps, sA * (long long)N_COMP + (j0 - N_CAUSES), ebf, evA);
            load16(eps, sB * (long long)N_COMP + (j0 - N_CAUSES), ebf, evB);
        }

        float acc0[16], acc1[16];
        #pragma unroll
        for (int i = 0; i < 16; ++i) { acc0[i] = 0.0f; acc1[i] = 0.0f; }

        // cause parents (registers, wave0 only; wave1 compensated with larger LDS range)
        if (wave == 0) {
            #pragma unroll
            for (int p = 0; p < N_CAUSES; ++p) {
                const float4* wr = (const float4*)(Wt + p * 16);
                float4 w0 = wr[0], w1 = wr[1], w2 = wr[2], w3 = wr[3];
                FMA16P(w0, w1, w2, w3, cv0[p], cv1[p])
            }
        }

        // computed parents from LDS, split between waves
        const int P0  = (j0 / 2 + 4) < 16 ? 16 : (j0 / 2 + 4);
        const int plo = wave ? P0 : 16;
        const int phi = wave ? j0 : P0;
        #pragma unroll 4
        for (int p = plo; p < phi; ++p) {
            const float4* wr = (const float4*)(Wt + p * 16);
            float4 w0 = wr[0], w1 = wr[1], w2 = wr[2], w3 = wr[3];
            const unsigned pv = *(const unsigned*)&vals[(p - N_CAUSES) * TSB + 2 * lane];
            const float2 vf = unpack_h2(pv);
            FMA16P(w0, w1, w2, w3, vf.x, vf.y)
        }

        __syncthreads();   // B1: all GEMM reads of Wt done

        // wave1 publishes partials (red aliases Wt: after tile for k<8, rows 0..127 for k>=8)
        float* red = (k < 8) ? (Wt + (j0 + 16) * 16) : Wt;
        if (wave == 1) {
            #pragma unroll
            for (int i = 0; i < 16; ++i) {
                float2 t; t.x = acc0[i]; t.y = acc1[i];
                *(float2*)&red[i * TSB + 2 * lane] = t;
            }
        }
        __syncthreads();   // B2

        if (wave == 0) {
            #pragma unroll
            for (int i = 0; i < 16; ++i) {
                const float2 t = *(const float2*)&red[i * TSB + 2 * lane];
                acc0[i] += t.x; acc1[i] += t.y;
            }
            // sequential intra-chunk tail (fp32), fp32 X/y stores, fp16 vals stores
            float vnA[16], vnB[16];
            #pragma unroll
            for (int i = 0; i < 16; ++i) {
                float zA = acc0[i], zB = acc1[i];
                #pragma unroll
                for (int l = 0; l < i; ++l) {
                    const float w = Wt[(j0 + l) * 16 + i];   // uniform (triangular rows)
                    zA += w * vnA[l]; zB += w * vnB[l];
                }
                zA += NOISE * evA[i]; zB += NOISE * evB[i];
                const int a = acts[j0 - N_CAUSES + i];       // uniform
                if (a == 1)      { zA = tanhf(zA); zB = tanhf(zB); }
                else if (a == 2) { zA = fmaxf(zA, 0.0f); zB = fmaxf(zB, 0.0f); }
                else if (a == 3) { zA = 1.0f/(1.0f+expf(-zA)); zB = 1.0f/(1.0f+expf(-zB)); }
                vnA[i] = zA; vnB[i] = zB;
                *(unsigned*)&vals[(j0 - N_CAUSES + i) * TSB + 2 * lane] = pack_h2(zA, zB);
                const int xp = xpos[j0 - N_CAUSES + i];      // uniform
                if (xp >= 0) {
                    out[sA * N_FEAT + xp] = zA;
                    out[sB * N_FEAT + xp] = zB;
                }
                if (j0 + i == yi) {                          // uniform
                    out[ybase + sA] = zA;
                    out[ybase + sB] = zB;
                }
            }
        }
        __syncthreads();   // B3: tail done, Wt free

        if (k < 15) {
            const int L = (16 * (k + 1) + 16) * 16, off = wpack_off(k + 1);
            for (int i = tid * 4; i < L; i += NTHREADS * 4)
                *(float4*)&Wt[i] = *(const float4*)&g_Wpack[off + i];
        }
        __syncthreads();   // B4: next tile staged
    }
}

extern "C" void kernel_launch(void* const* d_in, const int* in_sizes, int n_in,
                              void* d_out, int out_size, void* d_ws, size_t ws_size,
                              hipStream_t stream) {
    // resolve inputs by element count (permutation-proof); fall back to dict order
    int ic = 0, iw = 1, ie = 2, im = 3, ia = 4, ix = 5, iy = 6;
    int c = -1, e = -1, a = -1, x = -1, y = -1, m1 = -1, m2 = -1;
    for (int i = 0; i < n_in; ++i) {
        switch (in_sizes[i]) {
            case S_LEN * N_CAUSES:   c = i; break;
            case S_LEN * N_COMP:     e = i; break;
            case N_COMP:             a = i; break;
            case N_FEAT:             x = i; break;
            case 1:                  y = i; break;
            case N_NODES * N_NODES:  (m1 < 0 ? m1 : m2) = i; break;
        }
    }
    if (c >= 0 && e >= 0 && a >= 0 && x >= 0 && y >= 0 && m1 >= 0 && m2 >= 0) {
        ic = c; ie = e; ia = a; ix = x; iy = y; iw = m1; im = m2;
    }

    const void* causes = d_in[ic];
    const void* TA     = d_in[iw];   // one of {W, mask} — device disambiguates
    const void* TB     = d_in[im];
    const void* eps    = d_in[ie];
    const int*  act_id = (const int*)d_in[ia];
    const void* xidx   = d_in[ix];
    const int*  yidx   = (const int*)d_in[iy];
    float*      out    = (float*)d_out;
    const long long ybase = (long long)out_size - S_LEN;

    prep_kernel<<<dim3(16, 15), 256, 0, stream>>>(TA, TB);
    scm_kernel<<<S_LEN / TSB, NTHREADS, 0, stream>>>(causes, eps, act_id, xidx, yidx,
                                                     out, ybase);
}

// Round 9
// 443.987 us; speedup vs baseline: 3.4231x; 1.2531x over previous
//
#include <hip/hip_runtime.h>
#include <hip/hip_bf16.h>
#include <hip/hip_fp16.h>

// MLPSCM round 9: MFMA formulation. R8 was VALU-issue-bound (VALUBusy 24%,
// 30.7K scalar FMA instrs/wave). Replace the GEMM part with f16 MFMA:
//  - single-wave blocks (64 samples), no partner barriers, 4 blocks/CU (39 KB LDS)
//  - vals[64][256] scaled fp16, XOR-(row&7) 16B-slot swizzle (conflict-free A reads)
//  - W as hi+lo fp16 planes (residual 2^-22 -> W quant error eliminated),
//    prep-packed transposed [n][K] per chunk; B-frags = 16B global loads (L2-hot)
//  - K includes cause-rows 0..15; future rows zero => K rounds to 32 safely
//  - Z via C-layout->Zbuf(LDS, stride 21)->serial tail (fp32, 1 sample/lane)

typedef _Float16 half8 __attribute__((ext_vector_type(8)));
typedef float    f32x4 __attribute__((ext_vector_type(4)));

constexpr int S_LEN    = 131072;
constexpr int N_NODES  = 256;
constexpr int N_CAUSES = 16;
constexpr int N_COMP   = 240;
constexpr int N_FEAT   = 100;
constexpr float NOISE  = 0.01f;
constexpr float VSC    = 0.0625f;   // vals store scale 1/16
constexpr float VSCI   = 16.0f;

// K_eff per chunk (K=16k+16 rounded up to 32) and hi/lo-plane pack offsets
__constant__ int c_KE[16]  = {0,32,64,64,96,96,128,128,160,160,192,192,224,224,256,256};
__constant__ int c_OFF[16] = {0,0,1024,3072,5120,8192,11264,15360,19456,24576,29696,
                              35840,41984,49152,56320,64512};

__device__ _Float16 g_WT[72704];      // per chunk: [hi|lo] planes of [16 cols][KE] W^T
__device__ float    g_Wtri[15 * 256]; // per chunk: [l][i] in-chunk triangular W (fp32)

// ---------- content sniffers ----------
__device__ __forceinline__ bool sniff_binary64(const void* p) {
    const unsigned* u = (const unsigned*)p;
    bool ok = true;
    for (int i = 0; i < 64; ++i) ok = ok && (u[i] <= 1u);
    return ok;
}
__device__ __forceinline__ bool sniff_is_bf16(const void* p) {
    const unsigned* u = (const unsigned*)p;
    bool ok = true;
    for (int i = 0; i < 16; ++i) {
        unsigned e = ((u[i] << 16) >> 23) & 0xffu;
        ok = ok && (e >= 100u) && (e <= 132u);
    }
    return ok;
}
__device__ __forceinline__ float bflo(unsigned u) { return __uint_as_float(u << 16); }
__device__ __forceinline__ float bfhi(unsigned u) { return __uint_as_float(u & 0xffff0000u); }

__device__ __forceinline__ void load16(const void* base, long long off, bool isbf, float* o) {
    if (isbf) {
        const uint4* p = (const uint4*)((const unsigned short*)base + off);
        uint4 a = p[0], b = p[1];
        o[0]=bflo(a.x); o[1]=bfhi(a.x); o[2]=bflo(a.y); o[3]=bfhi(a.y);
        o[4]=bflo(a.z); o[5]=bfhi(a.z); o[6]=bflo(a.w); o[7]=bfhi(a.w);
        o[8]=bflo(b.x); o[9]=bfhi(b.x); o[10]=bflo(b.y); o[11]=bfhi(b.y);
        o[12]=bflo(b.z); o[13]=bfhi(b.z); o[14]=bflo(b.w); o[15]=bfhi(b.w);
    } else {
        const float4* p = (const float4*)((const float*)base + off);
        float4 x0=p[0], x1=p[1], x2=p[2], x3=p[3];
        o[0]=x0.x; o[1]=x0.y; o[2]=x0.z; o[3]=x0.w;
        o[4]=x1.x; o[5]=x1.y; o[6]=x1.z; o[7]=x1.w;
        o[8]=x2.x; o[9]=x2.y; o[10]=x2.z; o[11]=x2.w;
        o[12]=x3.x; o[13]=x3.y; o[14]=x3.z; o[15]=x3.w;
    }
}

// ---------- prep: pack W^T hi/lo fp16 per chunk + fp32 triangular ----------
__global__ void prep_kernel(const void* __restrict__ A, const void* __restrict__ B) {
    __shared__ int s_mA, s_wbf;
    if (threadIdx.x == 0) {
        s_mA  = sniff_binary64(A) ? 1 : 0;
        s_wbf = sniff_is_bf16(s_mA ? B : A) ? 1 : 0;
    }
    __syncthreads();
    const int*  maskp = (const int*)(s_mA ? A : B);
    const void* Wp    = s_mA ? B : A;
    const int k = blockIdx.x + 1, j0 = 16 * k, KE = c_KE[k], OFF = c_OFF[k];
    const int tid = threadIdx.x;

    for (int n = 0; n < 16; ++n) {
        const int j = j0 + n;
        for (int kk = tid; kk < KE; kk += 256) {
            const int gi = kk * N_NODES + j;
            float w = 0.0f;
            if (maskp[gi])
                w = s_wbf ? __bfloat162float(((const __hip_bfloat16*)Wp)[gi])
                          : ((const float*)Wp)[gi];
            const _Float16 hi = (_Float16)w;
            const _Float16 lo = (_Float16)(w - (float)hi);
            g_WT[OFF + n * KE + kk]           = hi;
            g_WT[OFF + 16 * KE + n * KE + kk] = lo;
        }
    }
    {   // triangular in-chunk weights, fp32
        const int l = tid >> 4, i = tid & 15;
        const int gi = (j0 + l) * N_NODES + (j0 + i);
        float w = 0.0f;
        if (l < i && maskp[gi])
            w = s_wbf ? __bfloat162float(((const __hip_bfloat16*)Wp)[gi])
                      : ((const float*)Wp)[gi];
        g_Wtri[(k - 1) * 256 + tid] = w;
    }
}

#define MFMA16(a, b, c) __builtin_amdgcn_mfma_f32_16x16x32_f16((a), (b), (c), 0, 0, 0)

__global__ __launch_bounds__(64)
void scm_kernel(const void* __restrict__ causes,
                const void* __restrict__ eps,
                const int* __restrict__ act_id,
                const void* __restrict__ xidx_raw,
                const int* __restrict__ yidx_raw,
                float* __restrict__ out,
                long long ybase) {
    __shared__ _Float16 vals[64 * 256];   // 32768 B, rows swizzled by (row&7) in 16B slots
    __shared__ float    Zbuf[64 * 21];    // 5376 B
    __shared__ short    xpos[N_COMP];     // 480 B
    __shared__ short    acts[N_COMP];     // 480 B

    const int lane = threadIdx.x;
    const long long sg = (long long)blockIdx.x * 64 + lane;

    for (int t = lane; t < N_COMP; t += 64) { xpos[t] = -1; acts[t] = (short)act_id[t]; }
    const unsigned long long* x64 = (const unsigned long long*)xidx_raw;
    const int*                x32 = (const int*)xidx_raw;
    const bool is64 = ((x64[0] >> 32) == 0ull);
    __syncthreads();
    for (int f = lane; f < N_FEAT; f += 64) {
        const int ix = is64 ? (int)x64[f] : x32[f];
        xpos[ix - N_CAUSES] = (short)f;
    }
    const int yi  = yidx_raw[0];
    const bool cbf = sniff_is_bf16(causes);
    const bool ebf = sniff_is_bf16(eps);

    // zero own row + write causes (scaled fp16) into logical slots 0,1
    {
        float cv[16];
        load16(causes, sg * N_CAUSES, cbf, cv);
        _Float16* row = vals + lane * 256;
        const uint4 z = {0u, 0u, 0u, 0u};
        #pragma unroll
        for (int s = 0; s < 32; ++s) *(uint4*)(row + s * 8) = z;
        const int swz = lane & 7;
        half8 c0, c1;
        #pragma unroll
        for (int i = 0; i < 8; ++i) {
            c0[i] = (_Float16)(cv[i] * VSC);
            c1[i] = (_Float16)(cv[8 + i] * VSC);
        }
        *(half8*)(row + ((0 ^ swz) << 3)) = c0;
        *(half8*)(row + ((1 ^ swz) << 3)) = c1;
    }
    __syncthreads();

    const int mrow = lane & 15;     // M-row within tile / B's n-col
    const int quad = lane >> 4;     // k-quad
    const int swzA = mrow & 7;

    for (int k = 1; k < 16; ++k) {
        const int j0 = 16 * k, KE = c_KE[k], nst = KE >> 5;
        const _Float16* bph = g_WT + c_OFF[k] + mrow * KE + (quad << 3);
        const _Float16* bpl = bph + 16 * KE;

        float ev[16];
        load16(eps, sg * (long long)N_COMP + (j0 - N_CAUSES), ebf, ev);

        f32x4 acc0 = {0.f,0.f,0.f,0.f}, acc1 = {0.f,0.f,0.f,0.f};
        f32x4 acc2 = {0.f,0.f,0.f,0.f}, acc3 = {0.f,0.f,0.f,0.f};

        for (int t = 0; t < nst; ++t) {
            const int co = (((4 * t + quad) ^ swzA) << 3);   // swizzled 16B slot
            half8 a0 = *(const half8*)(vals + (mrow     ) * 256 + co);
            half8 a1 = *(const half8*)(vals + (mrow + 16) * 256 + co);
            half8 a2 = *(const half8*)(vals + (mrow + 32) * 256 + co);
            half8 a3 = *(const half8*)(vals + (mrow + 48) * 256 + co);
            half8 bh = *(const half8*)(bph + (t << 5));
            half8 bl = *(const half8*)(bpl + (t << 5));
            acc0 = MFMA16(a0, bh, acc0); acc0 = MFMA16(a0, bl, acc0);
            acc1 = MFMA16(a1, bh, acc1); acc1 = MFMA16(a1, bl, acc1);
            acc2 = MFMA16(a2, bh, acc2); acc2 = MFMA16(a2, bl, acc2);
            acc3 = MFMA16(a3, bh, acc3); acc3 = MFMA16(a3, bl, acc3);
        }

        // C-layout (col=lane&15, row=quad*4+reg) -> Zbuf, unscaled
        {
            const int r0 = quad << 2, cc = mrow;
            #pragma unroll
            for (int r = 0; r < 4; ++r) {
                Zbuf[(r0 + r)      * 21 + cc] = acc0[r] * VSCI;
                Zbuf[(16 + r0 + r) * 21 + cc] = acc1[r] * VSCI;
                Zbuf[(32 + r0 + r) * 21 + cc] = acc2[r] * VSCI;
                Zbuf[(48 + r0 + r) * 21 + cc] = acc3[r] * VSCI;
            }
        }
        __syncthreads();

        // serial intra-chunk tail: sample = lane (fp32)
        {
            float vn[16];
            half8 h0, h1;
            const float* tri = g_Wtri + ((k - 1) << 8);
            #pragma unroll
            for (int i = 0; i < 16; ++i) {
                float z = Zbuf[lane * 21 + i] + NOISE * ev[i];
                #pragma unroll
                for (int l = 0; l < i; ++l) z += tri[(l << 4) + i] * vn[l];
                const int a = acts[j0 - N_CAUSES + i];   // wave-uniform
                if (a == 1)      z = tanhf(z);
                else if (a == 2) z = fmaxf(z, 0.0f);
                else if (a == 3) z = 1.0f / (1.0f + expf(-z));
                vn[i] = z;
                if (i < 8) h0[i] = (_Float16)(z * VSC);
                else       h1[i - 8] = (_Float16)(z * VSC);
                const int xp = xpos[j0 - N_CAUSES + i];  // wave-uniform
                if (xp >= 0) out[sg * N_FEAT + xp] = z;
                if (j0 + i == yi) out[ybase + sg] = z;
            }
            const int swz = lane & 7;
            const int s0  = j0 >> 3;
            _Float16* row = vals + lane * 256;
            *(half8*)(row + (((s0    ) ^ swz) << 3)) = h0;
            *(half8*)(row + (((s0 + 1) ^ swz) << 3)) = h1;
        }
        __syncthreads();
    }
}

extern "C" void kernel_launch(void* const* d_in, const int* in_sizes, int n_in,
                              void* d_out, int out_size, void* d_ws, size_t ws_size,
                              hipStream_t stream) {
    // resolve inputs by element count (permutation-proof); fall back to dict order
    int ic = 0, iw = 1, ie = 2, im = 3, ia = 4, ix = 5, iy = 6;
    int c = -1, e = -1, a = -1, x = -1, y = -1, m1 = -1, m2 = -1;
    for (int i = 0; i < n_in; ++i) {
        switch (in_sizes[i]) {
            case S_LEN * N_CAUSES:   c = i; break;
            case S_LEN * N_COMP:     e = i; break;
            case N_COMP:             a = i; break;
            case N_FEAT:             x = i; break;
            case 1:                  y = i; break;
            case N_NODES * N_NODES:  (m1 < 0 ? m1 : m2) = i; break;
        }
    }
    if (c >= 0 && e >= 0 && a >= 0 && x >= 0 && y >= 0 && m1 >= 0 && m2 >= 0) {
        ic = c; ie = e; ia = a; ix = x; iy = y; iw = m1; im = m2;
    }

    const void* causes = d_in[ic];
    const void* TA     = d_in[iw];   // one of {W, mask} — device disambiguates
    const void* TB     = d_in[im];
    const void* eps    = d_in[ie];
    const int*  act_id = (const int*)d_in[ia];
    const void* xidx   = d_in[ix];
    const int*  yidx   = (const int*)d_in[iy];
    float*      out    = (float*)d_out;
    const long long ybase = (long long)out_size - S_LEN;

    prep_kernel<<<15, 256, 0, stream>>>(TA, TB);
    scm_kernel<<<S_LEN / 64, 64, 0, stream>>>(causes, eps, act_id, xidx, yidx, out, ybase);
}